// Round 1
// baseline (1895.642 us; speedup 1.0000x reference)
//
#include <hip/hip_runtime.h>
#include <hip/hip_bf16.h>

// Problem constants: B=8, H=W=64, C=128, rate=2 -> k=3, h=w=32, L=1024
// Workspace arena (floats):
//   sp    [0        .. 1183744)   srcpad (8,34,34,128)
//   invd  [1183744  .. 1314816)   (1024,128)  1/denom, layout [l][c]
//   m0    [1314816  .. 1323008)   (8,32,32) pooled mask
//   mm    [1323008  .. 1331200)   (8,32,32) 1 - dilated mask
//   bufY  [1331200  .. 9719808)   8M floats: logits -> fuse2 out -> y_up[:4.19M]+dw1out[4.19M:] -> dw2out
//   bufT  [9719808  .. 18108416)  8M floats: fuse1 out -> a1[:4.19M]
// total 72,433,664 bytes

#define OFF_SP   0
#define OFF_INVD 1183744
#define OFF_M0   1314816
#define OFF_MM   1323008
#define OFF_Y    1331200
#define OFF_T    9719808

__global__ __launch_bounds__(256) void k_mask_pool(const float* __restrict__ mask, float* __restrict__ m0) {
    int blk = blockIdx.x;                 // b*1024 + p*32 + q
    int b = blk >> 10, pq = blk & 1023, p = pq >> 5, q = pq & 31;
    int t = threadIdx.x, dy = t >> 4, dx = t & 15;
    float v = mask[((size_t)(b * 512 + p * 16 + dy)) * 512 + q * 16 + dx];
#pragma unroll
    for (int o = 32; o; o >>= 1) v = fmaxf(v, __shfl_xor(v, o));
    __shared__ float s[4];
    if ((t & 63) == 0) s[t >> 6] = v;
    __syncthreads();
    if (t == 0) m0[blk] = fmaxf(fmaxf(s[0], s[1]), fmaxf(s[2], s[3]));
}

__global__ void k_mask_dilate(const float* __restrict__ m0, float* __restrict__ mm) {
    int idx = blockIdx.x * 256 + threadIdx.x;
    if (idx >= 8192) return;
    int b = idx >> 10, pq = idx & 1023, p = pq >> 5, q = pq & 31;
    float v = -1e30f;
    for (int di = -1; di <= 1; ++di)
        for (int dj = -1; dj <= 1; ++dj) {
            int pp = p + di, qq = q + dj;
            if (pp >= 0 && pp < 32 && qq >= 0 && qq < 32)
                v = fmaxf(v, m0[(b << 10) + pp * 32 + qq]);
        }
    mm[idx] = 1.0f - v;
}

__global__ void k_srcpad(const float* __restrict__ x, float* __restrict__ sp) {
    int idx = blockIdx.x * 256 + threadIdx.x;
    if (idx >= 8 * 34 * 34 * 128) return;
    int c = idx & 127;
    int r = idx >> 7;
    int xx = r % 34; r /= 34;
    int yy = r % 34; int b = r / 34;
    float v = 0.f;
    if (yy >= 1 && yy <= 32 && xx >= 1 && xx <= 32)
        v = x[(((size_t)(b * 64 + (yy - 1) * 2)) * 64 + (xx - 1) * 2) * 128 + c];
    sp[idx] = v;
}

__global__ void k_invd(const float* __restrict__ sp, float* __restrict__ invd) {
    int idx = blockIdx.x * 256 + threadIdx.x;
    if (idx >= 1024 * 128) return;
    int c = idx & 127, l = idx >> 7, lh = l >> 5, lw = l & 31;
    float s = 0.f;
    for (int b = 0; b < 8; ++b)
#pragma unroll
        for (int i = 0; i < 3; ++i)
#pragma unroll
            for (int j = 0; j < 3; ++j) {
                float v = sp[(((size_t)(b * 34 + lh + i)) * 34 + (lw + j)) * 128 + c];
                s += v * v;
            }
    invd[idx] = 1.0f / fmaxf(s, 1e-8f);
}

// corr GEMM: per batch y[pq,l] = sum_{k=(i,j,c)} A[pq,k]*B[k,l],
// A = srcpad patch at (p+i, q+j, c); B = srcpad patch at (lh+i, lw+j, c) * invd[l,c]
__global__ __launch_bounds__(256) void k_corr_gemm(const float* __restrict__ sp,
                                                   const float* __restrict__ invd,
                                                   float* __restrict__ y) {
    const int b = blockIdx.z, tm = blockIdx.y, tn = blockIdx.x;
    __shared__ float As[16][66];
    __shared__ float Bs[16][66];
    const int tid = threadIdx.x;
    const int ty = tid >> 4, tx = tid & 15;
    float acc[4][4] = {};
    for (int kt = 0; kt < 1152; kt += 16) {
#pragma unroll
        for (int it = 0; it < 4; ++it) {
            int e = tid + it * 256;
            int kk = e & 15, rc = e >> 4;   // rc in [0,64)
            int k = kt + kk;
            int c = k & 127, ij = k >> 7;
            int i = ij / 3, j = ij - 3 * i;
            {   // A
                int pq = tm * 64 + rc, p = pq >> 5, q = pq & 31;
                As[kk][rc] = sp[(((size_t)(b * 34 + p + i)) * 34 + (q + j)) * 128 + c];
            }
            {   // B
                int l = tn * 64 + rc, lh = l >> 5, lw = l & 31;
                Bs[kk][rc] = sp[(((size_t)(b * 34 + lh + i)) * 34 + (lw + j)) * 128 + c] * invd[l * 128 + c];
            }
        }
        __syncthreads();
#pragma unroll
        for (int kk = 0; kk < 16; ++kk) {
            float av[4], bv[4];
#pragma unroll
            for (int u = 0; u < 4; ++u) av[u] = As[kk][ty * 4 + u];
#pragma unroll
            for (int v = 0; v < 4; ++v) bv[v] = Bs[kk][tx * 4 + v];
#pragma unroll
            for (int u = 0; u < 4; ++u)
#pragma unroll
                for (int v = 0; v < 4; ++v) acc[u][v] = fmaf(av[u], bv[v], acc[u][v]);
        }
        __syncthreads();
    }
#pragma unroll
    for (int u = 0; u < 4; ++u) {
        int pq = tm * 64 + ty * 4 + u;
        float4 o = make_float4(acc[u][0], acc[u][1], acc[u][2], acc[u][3]);
        *reinterpret_cast<float4*>(&y[((size_t)(b * 1024 + pq)) * 1024 + tn * 64 + tx * 4]) = o;
    }
}

__global__ void k_fuse1(const float* __restrict__ in, float* __restrict__ out) {
    size_t idx = (size_t)blockIdx.x * 256 + threadIdx.x;
    if (idx >= (size_t)8 * 1024 * 1024) return;
    int t = (int)(idx & 1023);
    int s = (int)((idx >> 10) & 1023);
    int b = (int)(idx >> 20);
    const float* base = in + ((size_t)b << 20);
    float v = base[(size_t)s * 1024 + t];
    if (s > 0 && t > 0) v += base[(size_t)(s - 1) * 1024 + (t - 1)];
    if (s < 1023 && t < 1023) v += base[(size_t)(s + 1) * 1024 + (t + 1)];
    out[idx] = v;
}

// second fuse under the (p,q)<->(lh,lw) transposed permutation; writes standard layout
__global__ void k_fuse2(const float* __restrict__ in, float* __restrict__ out) {
    size_t idx = (size_t)blockIdx.x * 256 + threadIdx.x;
    if (idx >= (size_t)8 * 1024 * 1024) return;
    int t = (int)(idx & 1023);
    int s = (int)((idx >> 10) & 1023);
    int b = (int)(idx >> 20);
    int m0 = ((s & 31) << 5) + (s >> 5);
    int n0 = ((t & 31) << 5) + (t >> 5);
    const float* base = in + ((size_t)b << 20);
    float v = 0.f;
#pragma unroll
    for (int d = -1; d <= 1; ++d) {
        int m = m0 + d, n = n0 + d;
        if (m >= 0 && m < 1024 && n >= 0 && n < 1024)
            v += base[(size_t)(((m & 31) << 5) + (m >> 5)) * 1024 + (((n & 31) << 5) + (n >> 5))];
    }
    out[idx] = v;
}

__global__ __launch_bounds__(256) void k_softmax1024(const float* __restrict__ yv,
                                                     const float* __restrict__ mm,
                                                     float* __restrict__ outc) {
    int row = blockIdx.x;   // b*1024 + s
    const float* base = yv + (size_t)row * 1024;
    float mmv = mm[row];
    int t = threadIdx.x;
    float vals[4];
    float mx = -1e30f;
#pragma unroll
    for (int i = 0; i < 4; ++i) {
        vals[i] = base[t + i * 256] * mmv * 10.0f;
        mx = fmaxf(mx, vals[i]);
    }
#pragma unroll
    for (int o = 32; o; o >>= 1) mx = fmaxf(mx, __shfl_xor(mx, o));
    __shared__ float red[8];
    if ((t & 63) == 0) red[t >> 6] = mx;
    __syncthreads();
    mx = fmaxf(fmaxf(red[0], red[1]), fmaxf(red[2], red[3]));
    float s = 0.f;
#pragma unroll
    for (int i = 0; i < 4; ++i) {
        vals[i] = expf(vals[i] - mx);
        s += vals[i];
    }
#pragma unroll
    for (int o = 32; o; o >>= 1) s += __shfl_xor(s, o);
    if ((t & 63) == 0) red[4 + (t >> 6)] = s;
    __syncthreads();
    s = red[4] + red[5] + red[6] + red[7];
    float inv = mmv / s;
#pragma unroll
    for (int i = 0; i < 4; ++i)
        outc[(size_t)row * 1024 + t + i * 256] = vals[i] * inv;
}

// deconv GEMM: per batch Z[uv, k=(i',j',c)] = sum_l y[uv,l] * Xp[l,k];
// Xp[l,k] = x[b, 2*lh+i', 2*lw+j', c] (0 if >=64). Epilogue scatters into y_up.
__global__ __launch_bounds__(256) void k_deconv_gemm(const float* __restrict__ yf,
                                                     const float* __restrict__ x,
                                                     float* __restrict__ yup) {
    const int b = blockIdx.z, tm = blockIdx.y, tn = blockIdx.x;  // tn in [0,18)
    __shared__ float As[16][66];   // [kk=l][uv]
    __shared__ float Bs[16][66];   // [kk=l][kcol]
    const int tid = threadIdx.x;
    const int ty = tid >> 4, tx = tid & 15;
    float acc[4][4] = {};
    for (int kt = 0; kt < 1024; kt += 16) {
#pragma unroll
        for (int it = 0; it < 4; ++it) {
            {   // A: lanes along kk (contiguous l in memory)
                int e = tid + it * 256;
                int kk = e & 15, rc = e >> 4;
                int uv = tm * 64 + rc;
                As[kk][rc] = yf[((size_t)(b * 1024 + uv)) * 1024 + kt + kk];
            }
            {   // B: lanes along rc (contiguous c in memory)
                int e = tid + it * 256;
                int rc = e & 63, kk = e >> 6;
                int k = tn * 64 + rc;
                int c = k & 127, ij = k >> 7;
                int ip = ij / 3, jp = ij - 3 * ip;
                int l = kt + kk, lh = l >> 5, lw = l & 31;
                int rr = 2 * lh + ip, ss = 2 * lw + jp;
                Bs[kk][rc] = (rr < 64 && ss < 64) ? x[(((size_t)(b * 64 + rr)) * 64 + ss) * 128 + c] : 0.f;
            }
        }
        __syncthreads();
#pragma unroll
        for (int kk = 0; kk < 16; ++kk) {
            float av[4], bv[4];
#pragma unroll
            for (int u = 0; u < 4; ++u) av[u] = As[kk][ty * 4 + u];
#pragma unroll
            for (int v = 0; v < 4; ++v) bv[v] = Bs[kk][tx * 4 + v];
#pragma unroll
            for (int u = 0; u < 4; ++u)
#pragma unroll
                for (int v = 0; v < 4; ++v) acc[u][v] = fmaf(av[u], bv[v], acc[u][v]);
        }
        __syncthreads();
    }
#pragma unroll
    for (int u = 0; u < 4; ++u) {
        int uv = tm * 64 + ty * 4 + u;
        int uu = uv >> 5, vv = uv & 31;
#pragma unroll
        for (int v = 0; v < 4; ++v) {
            int k = tn * 64 + tx * 4 + v;
            int c = k & 127, ij = k >> 7;
            int ip = ij / 3, jp = ij - 3 * ip;
            int P = 2 * uu + ip, Q = 2 * vv + jp;
            if (P < 64 && Q < 64)
                atomicAdd(&yup[(((size_t)(b * 64 + P)) * 64 + Q) * 128 + c], acc[u][v]);
        }
    }
}

template <int CI>
__global__ void k_dw(const float* __restrict__ in0, const float* __restrict__ in1,
                     const float* __restrict__ dwW, float* __restrict__ out) {
    size_t idx = (size_t)blockIdx.x * 256 + threadIdx.x;
    if (idx >= (size_t)8 * 64 * 64 * CI) return;
    int c = (int)(idx % CI);
    size_t r = idx / CI;
    int Q = (int)(r & 63); r >>= 6;
    int P = (int)(r & 63);
    int b = (int)(r >> 6);
    float acc = 0.f;
#pragma unroll
    for (int i = 0; i < 3; ++i)
#pragma unroll
        for (int j = 0; j < 3; ++j) {
            int rr = P + i - 1, ss = Q + j - 1;
            if (rr < 0 || rr > 63 || ss < 0 || ss > 63) continue;
            float v;
            if (CI == 128 || c < 128)
                v = in0[(((size_t)(b * 64 + rr)) * 64 + ss) * 128 + (c & 127)];
            else
                v = in1[(((size_t)(b * 64 + rr)) * 64 + ss) * 128 + (c - 128)];
            acc += v * dwW[(i * 3 + j) * CI + c];
        }
    out[idx] = acc;
}

template <int CI>
__global__ __launch_bounds__(128) void k_pw_softmax(float* __restrict__ buf,
                                                    const float* __restrict__ pw,
                                                    const float* __restrict__ db) {
    __shared__ float row[CI];
    __shared__ float red[4];
    size_t pix = blockIdx.x;
    int t = threadIdx.x;
    float* base = buf + pix * CI;
    for (int i = t; i < CI; i += 128) row[i] = base[i];
    __syncthreads();
    float acc = db[t];
#pragma unroll 8
    for (int ci = 0; ci < CI; ++ci) acc = fmaf(row[ci], pw[ci * 128 + t], acc);
    float m = acc;
#pragma unroll
    for (int o = 32; o; o >>= 1) m = fmaxf(m, __shfl_xor(m, o));
    if ((t & 63) == 0) red[t >> 6] = m;
    __syncthreads();
    m = fmaxf(red[0], red[1]);
    float e = expf(acc - m);
    float s = e;
#pragma unroll
    for (int o = 32; o; o >>= 1) s += __shfl_xor(s, o);
    if ((t & 63) == 0) red[2 + (t >> 6)] = s;
    __syncthreads();
    s = red[2] + red[3];
    base[t] = e / s;   // in-place: first 128 slots of this pixel's row
}

template <int CI>
__global__ __launch_bounds__(128) void k_conv_gate(const float* __restrict__ in0,
                                                   const float* __restrict__ in1,
                                                   const float* __restrict__ w,
                                                   const float* __restrict__ bias,
                                                   const float* __restrict__ sm, int sm_stride,
                                                   float* __restrict__ out) {
    // block: b*1024 + P*16 + qg -> outputs (b, P, Q0..Q0+3, 0..127)
    int blk = blockIdx.x;
    int qg = blk & 15, P = (blk >> 4) & 63, b = blk >> 10;
    int Q0 = qg * 4;
    __shared__ float lds[18 * CI];
    int t = threadIdx.x;
    for (int e = t; e < 18 * CI; e += 128) {
        int ci = e % CI;
        int rc = e / CI;
        int rrow = rc / 6, col = rc % 6;
        int gr = P - 1 + rrow, gc = Q0 - 1 + col;
        float v = 0.f;
        if (gr >= 0 && gr < 64 && gc >= 0 && gc < 64) {
            if (CI == 128 || ci < 128)
                v = in0[(((size_t)(b * 64 + gr)) * 64 + gc) * 128 + (ci & 127)];
            else
                v = in1[(((size_t)(b * 64 + gr)) * 64 + gc) * 128 + (ci - 128)];
        }
        lds[rc * CI + ci] = v;
    }
    __syncthreads();
    float acc[4] = {};
    const int co = t;
#pragma unroll
    for (int i = 0; i < 3; ++i)
#pragma unroll
        for (int j = 0; j < 3; ++j) {
            const float* wp = w + ((size_t)(i * 3 + j) * CI) * 128 + co;
            const float* lp = lds + (i * 6 + j) * CI;
#pragma unroll 4
            for (int ci = 0; ci < CI; ++ci) {
                float wv = wp[(size_t)ci * 128];
                acc[0] = fmaf(lp[ci], wv, acc[0]);
                acc[1] = fmaf(lp[CI + ci], wv, acc[1]);
                acc[2] = fmaf(lp[2 * CI + ci], wv, acc[2]);
                acc[3] = fmaf(lp[3 * CI + ci], wv, acc[3]);
            }
        }
    float bb = bias[co];
#pragma unroll
    for (int q = 0; q < 4; ++q) {
        float z = acc[q] + bb;
        z = z > 0.f ? z : expm1f(z);
        size_t pix = ((size_t)(b * 64 + P)) * 64 + (Q0 + q);
        out[pix * 128 + co] = z * sm[pix * sm_stride + co];
    }
}

extern "C" void kernel_launch(void* const* d_in, const int* in_sizes, int n_in,
                              void* d_out, int out_size, void* d_ws, size_t ws_size,
                              hipStream_t stream) {
    const float* x    = (const float*)d_in[0];
    const float* mask = (const float*)d_in[1];
    const float* w1   = (const float*)d_in[2];
    const float* b1   = (const float*)d_in[3];
    const float* dw1  = (const float*)d_in[4];
    const float* pw1  = (const float*)d_in[5];
    const float* db1  = (const float*)d_in[6];
    const float* w2   = (const float*)d_in[7];
    const float* b2   = (const float*)d_in[8];
    const float* dw2  = (const float*)d_in[9];
    const float* pw2  = (const float*)d_in[10];
    const float* db2  = (const float*)d_in[11];

    float* out_a = (float*)d_out;            // (8,64,64,128)
    float* out_c = out_a + 4194304;          // (8,32,32,1024)

    float* wsf  = (float*)d_ws;
    float* sp   = wsf + OFF_SP;
    float* invd = wsf + OFF_INVD;
    float* m0   = wsf + OFF_M0;
    float* mmb  = wsf + OFF_MM;
    float* bufY = wsf + OFF_Y;
    float* bufT = wsf + OFF_T;
    float* yup  = bufY;                       // (8,64,64,128)
    float* dw1o = bufY + 4194304;             // (8,64,64,128) -> sm1 in place
    float* a1   = bufT;                       // (8,64,64,128)
    float* dw2o = bufY;                       // (8,64,64,256) -> sm2 in place (stride 256)

    k_mask_pool<<<8192, 256, 0, stream>>>(mask, m0);
    k_mask_dilate<<<32, 256, 0, stream>>>(m0, mmb);
    k_srcpad<<<4624, 256, 0, stream>>>(x, sp);
    k_invd<<<512, 256, 0, stream>>>(sp, invd);
    k_corr_gemm<<<dim3(16, 16, 8), 256, 0, stream>>>(sp, invd, bufY);
    k_fuse1<<<32768, 256, 0, stream>>>(bufY, bufT);
    k_fuse2<<<32768, 256, 0, stream>>>(bufT, bufY);
    k_softmax1024<<<8192, 256, 0, stream>>>(bufY, mmb, out_c);
    hipMemsetAsync(yup, 0, (size_t)4194304 * sizeof(float), stream);
    k_deconv_gemm<<<dim3(18, 16, 8), 256, 0, stream>>>(out_c, x, yup);
    k_dw<128><<<16384, 256, 0, stream>>>(yup, nullptr, dw1, dw1o);
    k_pw_softmax<128><<<32768, 128, 0, stream>>>(dw1o, pw1, db1);
    k_conv_gate<128><<<8192, 128, 0, stream>>>(yup, nullptr, w1, b1, dw1o, 128, a1);
    k_dw<256><<<32768, 256, 0, stream>>>(a1, x, dw2, dw2o);
    k_pw_softmax<256><<<32768, 128, 0, stream>>>(dw2o, pw2, db2);
    k_conv_gate<256><<<8192, 128, 0, stream>>>(a1, x, w2, b2, dw2o, 256, out_a);
}

// Round 2
// 1365.363 us; speedup vs baseline: 1.3884x; 1.3884x over previous
//
#include <hip/hip_runtime.h>
#include <hip/hip_bf16.h>

// B=8, H=W=64, C=128, rate=2 -> k=3, h=w=32, L=1024
// Workspace arena (bytes), total 72,433,664 (same as round 0):
//   SP     [0 .. 4,734,976)          srcpad (8,34,34,128) f32   | later: weight bf16 overlays
//   INVD   [4,734,976 .. 5,259,264)  (1024,128) f32
//   M0     [5,259,264 .. 5,292,032)
//   MM     [5,292,032 .. 5,324,800)
//   A1     [5,324,800 .. 38,879,232) 8M f32: logits ping  | later: SM(4.19M f32) + Xpair(16.8MB)
//   A2     [38,879,232 .. 55,656,448) 4.19M f32: yup -> a1
//   P3     [55,656,448 .. 72,433,664) bf16 pair region (hi,lo) for yup-pair then a1-pair

#define BOFF_SP      0
#define BOFF_INVD    4734976
#define BOFF_M0      5259264
#define BOFF_MM      5292032
#define BOFF_A1      5324800
#define BOFF_SM      5324800
#define BOFF_XH      22102016
#define BOFF_XL      30490624
#define BOFF_A2      38879232
#define BOFF_P3H     55656448
#define BOFF_P3L     64045056
// weight overlays inside SP region (valid after k_corr_gemm):
#define BOFF_WT1H    0
#define BOFF_WT1L    294912
#define BOFF_WT2H    589824
#define BOFF_WT2L    1179648
#define BOFF_PW1B    1769472
#define BOFF_PW2B    1802240

typedef float f32x4 __attribute__((ext_vector_type(4)));
typedef short bf16x8 __attribute__((ext_vector_type(8)));

__device__ __forceinline__ short f2bf(float f) {
    unsigned u = __float_as_uint(f);
    unsigned r = u + 0x7FFFu + ((u >> 16) & 1u);
    return (short)(r >> 16);
}
__device__ __forceinline__ float bf2f(short s) {
    return __uint_as_float(((unsigned)(unsigned short)s) << 16);
}

__global__ __launch_bounds__(256) void k_mask_pool(const float* __restrict__ mask, float* __restrict__ m0) {
    int blk = blockIdx.x;
    int b = blk >> 10, pq = blk & 1023, p = pq >> 5, q = pq & 31;
    int t = threadIdx.x, dy = t >> 4, dx = t & 15;
    float v = mask[((size_t)(b * 512 + p * 16 + dy)) * 512 + q * 16 + dx];
#pragma unroll
    for (int o = 32; o; o >>= 1) v = fmaxf(v, __shfl_xor(v, o));
    __shared__ float s[4];
    if ((t & 63) == 0) s[t >> 6] = v;
    __syncthreads();
    if (t == 0) m0[blk] = fmaxf(fmaxf(s[0], s[1]), fmaxf(s[2], s[3]));
}

__global__ void k_mask_dilate(const float* __restrict__ m0, float* __restrict__ mm) {
    int idx = blockIdx.x * 256 + threadIdx.x;
    if (idx >= 8192) return;
    int b = idx >> 10, pq = idx & 1023, p = pq >> 5, q = pq & 31;
    float v = -1e30f;
    for (int di = -1; di <= 1; ++di)
        for (int dj = -1; dj <= 1; ++dj) {
            int pp = p + di, qq = q + dj;
            if (pp >= 0 && pp < 32 && qq >= 0 && qq < 32)
                v = fmaxf(v, m0[(b << 10) + pp * 32 + qq]);
        }
    mm[idx] = 1.0f - v;
}

__global__ void k_srcpad(const float* __restrict__ x, float* __restrict__ sp) {
    int idx = blockIdx.x * 256 + threadIdx.x;
    if (idx >= 8 * 34 * 34 * 128) return;
    int c = idx & 127;
    int r = idx >> 7;
    int xx = r % 34; r /= 34;
    int yy = r % 34; int b = r / 34;
    float v = 0.f;
    if (yy >= 1 && yy <= 32 && xx >= 1 && xx <= 32)
        v = x[(((size_t)(b * 64 + (yy - 1) * 2)) * 64 + (xx - 1) * 2) * 128 + c];
    sp[idx] = v;
}

__global__ void k_invd(const float* __restrict__ sp, float* __restrict__ invd) {
    int idx = blockIdx.x * 256 + threadIdx.x;
    if (idx >= 1024 * 128) return;
    int c = idx & 127, l = idx >> 7, lh = l >> 5, lw = l & 31;
    float s = 0.f;
    for (int b = 0; b < 8; ++b)
#pragma unroll
        for (int i = 0; i < 3; ++i)
#pragma unroll
            for (int j = 0; j < 3; ++j) {
                float v = sp[(((size_t)(b * 34 + lh + i)) * 34 + (lw + j)) * 128 + c];
                s += v * v;
            }
    invd[idx] = 1.0f / fmaxf(s, 1e-8f);
}

__global__ __launch_bounds__(256) void k_corr_gemm(const float* __restrict__ sp,
                                                   const float* __restrict__ invd,
                                                   float* __restrict__ y) {
    const int b = blockIdx.z, tm = blockIdx.y, tn = blockIdx.x;
    __shared__ float As[16][66];
    __shared__ float Bs[16][66];
    const int tid = threadIdx.x;
    const int ty = tid >> 4, tx = tid & 15;
    float acc[4][4] = {};
    for (int kt = 0; kt < 1152; kt += 16) {
#pragma unroll
        for (int it = 0; it < 4; ++it) {
            int e = tid + it * 256;
            int kk = e & 15, rc = e >> 4;
            int k = kt + kk;
            int c = k & 127, ij = k >> 7;
            int i = ij / 3, j = ij - 3 * i;
            {
                int pq = tm * 64 + rc, p = pq >> 5, q = pq & 31;
                As[kk][rc] = sp[(((size_t)(b * 34 + p + i)) * 34 + (q + j)) * 128 + c];
            }
            {
                int l = tn * 64 + rc, lh = l >> 5, lw = l & 31;
                Bs[kk][rc] = sp[(((size_t)(b * 34 + lh + i)) * 34 + (lw + j)) * 128 + c] * invd[l * 128 + c];
            }
        }
        __syncthreads();
#pragma unroll
        for (int kk = 0; kk < 16; ++kk) {
            float av[4], bv[4];
#pragma unroll
            for (int u = 0; u < 4; ++u) av[u] = As[kk][ty * 4 + u];
#pragma unroll
            for (int v = 0; v < 4; ++v) bv[v] = Bs[kk][tx * 4 + v];
#pragma unroll
            for (int u = 0; u < 4; ++u)
#pragma unroll
                for (int v = 0; v < 4; ++v) acc[u][v] = fmaf(av[u], bv[v], acc[u][v]);
        }
        __syncthreads();
    }
#pragma unroll
    for (int u = 0; u < 4; ++u) {
        int pq = tm * 64 + ty * 4 + u;
        float4 o = make_float4(acc[u][0], acc[u][1], acc[u][2], acc[u][3]);
        *reinterpret_cast<float4*>(&y[((size_t)(b * 1024 + pq)) * 1024 + tn * 64 + tx * 4]) = o;
    }
}

__global__ void k_fuse1(const float* __restrict__ in, float* __restrict__ out) {
    size_t idx = (size_t)blockIdx.x * 256 + threadIdx.x;
    if (idx >= (size_t)8 * 1024 * 1024) return;
    int t = (int)(idx & 1023);
    int s = (int)((idx >> 10) & 1023);
    int b = (int)(idx >> 20);
    const float* base = in + ((size_t)b << 20);
    float v = base[(size_t)s * 1024 + t];
    if (s > 0 && t > 0) v += base[(size_t)(s - 1) * 1024 + (t - 1)];
    if (s < 1023 && t < 1023) v += base[(size_t)(s + 1) * 1024 + (t + 1)];
    out[idx] = v;
}

__global__ void k_fuse2(const float* __restrict__ in, float* __restrict__ out) {
    size_t idx = (size_t)blockIdx.x * 256 + threadIdx.x;
    if (idx >= (size_t)8 * 1024 * 1024) return;
    int t = (int)(idx & 1023);
    int s = (int)((idx >> 10) & 1023);
    int b = (int)(idx >> 20);
    int m0 = ((s & 31) << 5) + (s >> 5);
    int n0 = ((t & 31) << 5) + (t >> 5);
    const float* base = in + ((size_t)b << 20);
    float v = 0.f;
#pragma unroll
    for (int d = -1; d <= 1; ++d) {
        int m = m0 + d, n = n0 + d;
        if (m >= 0 && m < 1024 && n >= 0 && n < 1024)
            v += base[(size_t)(((m & 31) << 5) + (m >> 5)) * 1024 + (((n & 31) << 5) + (n >> 5))];
    }
    out[idx] = v;
}

__global__ __launch_bounds__(256) void k_softmax1024(const float* __restrict__ yv,
                                                     const float* __restrict__ mm,
                                                     float* __restrict__ outc) {
    int row = blockIdx.x;
    const float* base = yv + (size_t)row * 1024;
    float mmv = mm[row];
    int t = threadIdx.x;
    float vals[4];
    float mx = -1e30f;
#pragma unroll
    for (int i = 0; i < 4; ++i) {
        vals[i] = base[t + i * 256] * mmv * 10.0f;
        mx = fmaxf(mx, vals[i]);
    }
#pragma unroll
    for (int o = 32; o; o >>= 1) mx = fmaxf(mx, __shfl_xor(mx, o));
    __shared__ float red[8];
    if ((t & 63) == 0) red[t >> 6] = mx;
    __syncthreads();
    mx = fmaxf(fmaxf(red[0], red[1]), fmaxf(red[2], red[3]));
    float s = 0.f;
#pragma unroll
    for (int i = 0; i < 4; ++i) {
        vals[i] = expf(vals[i] - mx);
        s += vals[i];
    }
#pragma unroll
    for (int o = 32; o; o >>= 1) s += __shfl_xor(s, o);
    if ((t & 63) == 0) red[4 + (t >> 6)] = s;
    __syncthreads();
    s = red[4] + red[5] + red[6] + red[7];
    float inv = mmv / s;
#pragma unroll
    for (int i = 0; i < 4; ++i)
        outc[(size_t)row * 1024 + t + i * 256] = vals[i] * inv;
}

__global__ __launch_bounds__(256) void k_deconv_gemm(const float* __restrict__ yf,
                                                     const float* __restrict__ x,
                                                     float* __restrict__ yup) {
    const int b = blockIdx.z, tm = blockIdx.y, tn = blockIdx.x;
    __shared__ float As[16][66];
    __shared__ float Bs[16][66];
    const int tid = threadIdx.x;
    const int ty = tid >> 4, tx = tid & 15;
    float acc[4][4] = {};
    for (int kt = 0; kt < 1024; kt += 16) {
#pragma unroll
        for (int it = 0; it < 4; ++it) {
            {
                int e = tid + it * 256;
                int kk = e & 15, rc = e >> 4;
                int uv = tm * 64 + rc;
                As[kk][rc] = yf[((size_t)(b * 1024 + uv)) * 1024 + kt + kk];
            }
            {
                int e = tid + it * 256;
                int rc = e & 63, kk = e >> 6;
                int k = tn * 64 + rc;
                int c = k & 127, ij = k >> 7;
                int ip = ij / 3, jp = ij - 3 * ip;
                int l = kt + kk, lh = l >> 5, lw = l & 31;
                int rr = 2 * lh + ip, ss = 2 * lw + jp;
                Bs[kk][rc] = (rr < 64 && ss < 64) ? x[(((size_t)(b * 64 + rr)) * 64 + ss) * 128 + c] : 0.f;
            }
        }
        __syncthreads();
#pragma unroll
        for (int kk = 0; kk < 16; ++kk) {
            float av[4], bv[4];
#pragma unroll
            for (int u = 0; u < 4; ++u) av[u] = As[kk][ty * 4 + u];
#pragma unroll
            for (int v = 0; v < 4; ++v) bv[v] = Bs[kk][tx * 4 + v];
#pragma unroll
            for (int u = 0; u < 4; ++u)
#pragma unroll
                for (int v = 0; v < 4; ++v) acc[u][v] = fmaf(av[u], bv[v], acc[u][v]);
        }
        __syncthreads();
    }
#pragma unroll
    for (int u = 0; u < 4; ++u) {
        int uv = tm * 64 + ty * 4 + u;
        int uu = uv >> 5, vv = uv & 31;
#pragma unroll
        for (int v = 0; v < 4; ++v) {
            int k = tn * 64 + tx * 4 + v;
            int c = k & 127, ij = k >> 7;
            int ip = ij / 3, jp = ij - 3 * ip;
            int P = 2 * uu + ip, Q = 2 * vv + jp;
            if (P < 64 && Q < 64)
                atomicAdd(&yup[(((size_t)(b * 64 + P)) * 64 + Q) * 128 + c], acc[u][v]);
        }
    }
}

// float image -> bf16 hi/lo planes (n = 4,194,304 fixed, 4 elems/thread)
__global__ __launch_bounds__(256) void k_pair(const float* __restrict__ in,
                                              short* __restrict__ hi, short* __restrict__ lo) {
    int idx = blockIdx.x * 256 + threadIdx.x;
    float4 v = reinterpret_cast<const float4*>(in)[idx];
    short4 h, L;
    float f, r;
    f = v.x; h.x = f2bf(f); r = f - bf2f(h.x); L.x = f2bf(r);
    f = v.y; h.y = f2bf(f); r = f - bf2f(h.y); L.y = f2bf(r);
    f = v.z; h.z = f2bf(f); r = f - bf2f(h.z); L.z = f2bf(r);
    f = v.w; h.w = f2bf(f); r = f - bf2f(h.w); L.w = f2bf(r);
    reinterpret_cast<short4*>(hi)[idx] = h;
    reinterpret_cast<short4*>(lo)[idx] = L;
}

// (3,3,CI,128) f32 -> [9][co=128][ci=CI] bf16 hi/lo
__global__ void k_wt_pair(const float* __restrict__ w, short* __restrict__ hi,
                          short* __restrict__ lo, int CI) {
    int idx = blockIdx.x * 256 + threadIdx.x;
    if (idx >= 9 * CI * 128) return;
    int ci = idx % CI; int rest = idx / CI;
    int co = rest & 127; int ij = rest >> 7;
    float v = w[((size_t)ij * CI + ci) * 128 + co];
    short h = f2bf(v);
    hi[idx] = h;
    lo[idx] = f2bf(v - bf2f(h));
}

__global__ void k_pw_bf16(const float* __restrict__ pw, short* __restrict__ out, int n) {
    int idx = blockIdx.x * 256 + threadIdx.x;
    if (idx < n) out[idx] = f2bf(pw[idx]);
}

// fused depthwise 3x3 + pointwise(CI->128) + channel softmax -> sm (stride 128)
template <int CI>
__global__ __launch_bounds__(128) void k_dwpw_sm(const float* __restrict__ in0,
                                                 const float* __restrict__ in1,
                                                 const float* __restrict__ dwW,
                                                 const short* __restrict__ pwb,
                                                 const float* __restrict__ db,
                                                 float* __restrict__ smout) {
    int pix = blockIdx.x;
    int b = pix >> 12, P = (pix >> 6) & 63, Q = pix & 63;
    __shared__ float row[CI];
    __shared__ float red[4];
    int t = threadIdx.x;
    for (int c = t; c < CI; c += 128) {
        float acc = 0.f;
#pragma unroll
        for (int i = 0; i < 3; ++i) {
            int rr = P + i - 1;
            if (rr < 0 || rr > 63) continue;
#pragma unroll
            for (int j = 0; j < 3; ++j) {
                int ss = Q + j - 1;
                if (ss < 0 || ss > 63) continue;
                float v = (CI == 128 || c < 128)
                              ? in0[(((size_t)(b * 64 + rr)) * 64 + ss) * 128 + (c & 127)]
                              : in1[(((size_t)(b * 64 + rr)) * 64 + ss) * 128 + (c - 128)];
                acc = fmaf(v, dwW[(i * 3 + j) * CI + c], acc);
            }
        }
        row[c] = acc;
    }
    __syncthreads();
    float acc = db[t];
#pragma unroll 8
    for (int ci = 0; ci < CI; ++ci)
        acc = fmaf(row[ci], bf2f(pwb[(size_t)ci * 128 + t]), acc);
    float m = acc;
#pragma unroll
    for (int o = 32; o; o >>= 1) m = fmaxf(m, __shfl_xor(m, o));
    if ((t & 63) == 0) red[t >> 6] = m;
    __syncthreads();
    m = fmaxf(red[0], red[1]);
    float e = expf(acc - m);
    float s = e;
#pragma unroll
    for (int o = 32; o; o >>= 1) s += __shfl_xor(s, o);
    if ((t & 63) == 0) red[2 + (t >> 6)] = s;
    __syncthreads();
    s = red[2] + red[3];
    smout[(size_t)pix * 128 + t] = e / s;
}

// MFMA split-bf16 implicit-GEMM 3x3 conv + bias + elu + gate multiply
// block: row P of batch b (64 pixels x 128 co). 4 waves, wave -> 2 co-tiles x 64 pixels.
template <int CI>
__global__ __launch_bounds__(256) void k_conv_mfma(const short* __restrict__ in0h,
                                                   const short* __restrict__ in0l,
                                                   const short* __restrict__ in1h,
                                                   const short* __restrict__ in1l,
                                                   const short* __restrict__ wh,
                                                   const short* __restrict__ wl,
                                                   const float* __restrict__ bias,
                                                   const float* __restrict__ sm,
                                                   float* __restrict__ out) {
    const int P = blockIdx.x, b = blockIdx.y;
    const int wv = threadIdx.x >> 6, l = threadIdx.x & 63;
    const int m = l & 15, g = l >> 4;
    bf16x8 zf;
#pragma unroll
    for (int t = 0; t < 8; ++t) zf[t] = 0;
    f32x4 acc[4][2];
#pragma unroll
    for (int mt = 0; mt < 4; ++mt)
#pragma unroll
        for (int nn = 0; nn < 2; ++nn) acc[mt][nn] = f32x4{0.f, 0.f, 0.f, 0.f};

    const size_t imgbase = ((size_t)b * 64) * 64 * 128;
#pragma unroll
    for (int i = 0; i < 3; ++i) {
        const int row = P + i - 1;
        if (row < 0 || row > 63) continue;
#pragma unroll
        for (int j = 0; j < 3; ++j) {
            const int ij = i * 3 + j;
            int Qp[4];
            bool okp[4];
#pragma unroll
            for (int mt = 0; mt < 4; ++mt) {
                int Q = mt * 16 + m + j - 1;
                okp[mt] = (Q >= 0) && (Q < 64);
                Qp[mt] = okp[mt] ? Q : 0;
            }
#pragma unroll
            for (int ci0 = 0; ci0 < CI; ci0 += 32) {
                const short* sh = (CI == 256 && ci0 >= 128) ? in1h : in0h;
                const short* sl = (CI == 256 && ci0 >= 128) ? in1l : in0l;
                const int cil = (CI == 256 && ci0 >= 128) ? (ci0 - 128) : ci0;
                bf16x8 ah[4], al[4];
#pragma unroll
                for (int mt = 0; mt < 4; ++mt) {
                    size_t off = imgbase + ((size_t)row * 64 + Qp[mt]) * 128 + cil + g * 8;
                    ah[mt] = okp[mt] ? *reinterpret_cast<const bf16x8*>(sh + off) : zf;
                    al[mt] = okp[mt] ? *reinterpret_cast<const bf16x8*>(sl + off) : zf;
                }
#pragma unroll
                for (int nn = 0; nn < 2; ++nn) {
                    const int co = (wv * 2 + nn) * 16 + m;
                    const size_t woff = ((size_t)ij * 128 + co) * CI + ci0 + g * 8;
                    bf16x8 bh = *reinterpret_cast<const bf16x8*>(wh + woff);
                    bf16x8 bl = *reinterpret_cast<const bf16x8*>(wl + woff);
#pragma unroll
                    for (int mt = 0; mt < 4; ++mt) {
                        acc[mt][nn] = __builtin_amdgcn_mfma_f32_16x16x32_bf16(ah[mt], bh, acc[mt][nn], 0, 0, 0);
                        acc[mt][nn] = __builtin_amdgcn_mfma_f32_16x16x32_bf16(ah[mt], bl, acc[mt][nn], 0, 0, 0);
                        acc[mt][nn] = __builtin_amdgcn_mfma_f32_16x16x32_bf16(al[mt], bh, acc[mt][nn], 0, 0, 0);
                    }
                }
            }
        }
    }
#pragma unroll
    for (int nn = 0; nn < 2; ++nn) {
        const int co = (wv * 2 + nn) * 16 + m;
        const float bb = bias[co];
#pragma unroll
        for (int mt = 0; mt < 4; ++mt) {
#pragma unroll
            for (int r = 0; r < 4; ++r) {
                int Q = mt * 16 + g * 4 + r;
                size_t pix = ((size_t)b * 64 + P) * 64 + Q;
                float z = acc[mt][nn][r] + bb;
                z = z > 0.f ? z : expm1f(z);
                out[pix * 128 + co] = z * sm[pix * 128 + co];
            }
        }
    }
}

extern "C" void kernel_launch(void* const* d_in, const int* in_sizes, int n_in,
                              void* d_out, int out_size, void* d_ws, size_t ws_size,
                              hipStream_t stream) {
    const float* x    = (const float*)d_in[0];
    const float* mask = (const float*)d_in[1];
    const float* w1   = (const float*)d_in[2];
    const float* b1   = (const float*)d_in[3];
    const float* dw1  = (const float*)d_in[4];
    const float* pw1  = (const float*)d_in[5];
    const float* db1  = (const float*)d_in[6];
    const float* w2   = (const float*)d_in[7];
    const float* b2   = (const float*)d_in[8];
    const float* dw2  = (const float*)d_in[9];
    const float* pw2  = (const float*)d_in[10];
    const float* db2  = (const float*)d_in[11];

    float* out_a = (float*)d_out;            // (8,64,64,128)
    float* out_c = out_a + 4194304;          // (8,32,32,1024)

    char* wsb = (char*)d_ws;
    float* sp   = (float*)(wsb + BOFF_SP);
    float* invd = (float*)(wsb + BOFF_INVD);
    float* m0   = (float*)(wsb + BOFF_M0);
    float* mmb  = (float*)(wsb + BOFF_MM);
    float* A1f  = (float*)(wsb + BOFF_A1);
    float* smb  = (float*)(wsb + BOFF_SM);
    short* xh   = (short*)(wsb + BOFF_XH);
    short* xl   = (short*)(wsb + BOFF_XL);
    float* A2f  = (float*)(wsb + BOFF_A2);   // yup then a1
    short* p3h  = (short*)(wsb + BOFF_P3H);
    short* p3l  = (short*)(wsb + BOFF_P3L);
    short* wt1h = (short*)(wsb + BOFF_WT1H);
    short* wt1l = (short*)(wsb + BOFF_WT1L);
    short* wt2h = (short*)(wsb + BOFF_WT2H);
    short* wt2l = (short*)(wsb + BOFF_WT2L);
    short* pw1b = (short*)(wsb + BOFF_PW1B);
    short* pw2b = (short*)(wsb + BOFF_PW2B);

    // phase A: mask + correlation + fuse + softmax
    k_mask_pool<<<8192, 256, 0, stream>>>(mask, m0);
    k_mask_dilate<<<32, 256, 0, stream>>>(m0, mmb);
    k_srcpad<<<4624, 256, 0, stream>>>(x, sp);
    k_invd<<<512, 256, 0, stream>>>(sp, invd);
    k_corr_gemm<<<dim3(16, 16, 8), 256, 0, stream>>>(sp, invd, A1f);
    // sp/invd now dead -> weight overlays
    k_wt_pair<<<576, 256, 0, stream>>>(w1, wt1h, wt1l, 128);
    k_wt_pair<<<1152, 256, 0, stream>>>(w2, wt2h, wt2l, 256);
    k_pw_bf16<<<64, 256, 0, stream>>>(pw1, pw1b, 16384);
    k_pw_bf16<<<128, 256, 0, stream>>>(pw2, pw2b, 32768);
    k_fuse1<<<32768, 256, 0, stream>>>(A1f, out_c);
    k_fuse2<<<32768, 256, 0, stream>>>(out_c, A1f);
    k_softmax1024<<<8192, 256, 0, stream>>>(A1f, mmb, out_c);
    // A1 free now
    k_pair<<<4096, 256, 0, stream>>>(x, xh, xl);
    // phase B: deconv -> yup (A2)
    hipMemsetAsync(A2f, 0, (size_t)4194304 * sizeof(float), stream);
    k_deconv_gemm<<<dim3(18, 16, 8), 256, 0, stream>>>(out_c, x, A2f);
    // phase C: gated conv 1
    k_dwpw_sm<128><<<32768, 128, 0, stream>>>(A2f, nullptr, dw1, pw1b, db1, smb);
    k_pair<<<4096, 256, 0, stream>>>(A2f, p3h, p3l);
    k_conv_mfma<128><<<dim3(64, 8), 256, 0, stream>>>(p3h, p3l, nullptr, nullptr,
                                                      wt1h, wt1l, b1, smb, A2f);
    // phase D: gated conv 2 (input concat(a1, x))
    k_dwpw_sm<256><<<32768, 128, 0, stream>>>(A2f, x, dw2, pw2b, db2, smb);
    k_pair<<<4096, 256, 0, stream>>>(A2f, p3h, p3l);
    k_conv_mfma<256><<<dim3(64, 8), 256, 0, stream>>>(p3h, p3l, xh, xl,
                                                      wt2h, wt2l, b2, smb, out_a);
}

// Round 3
// 924.087 us; speedup vs baseline: 2.0514x; 1.4775x over previous
//
#include <hip/hip_runtime.h>
#include <hip/hip_bf16.h>

// B=8, H=W=64, C=128, rate=2 -> k=3, h=w=32, L=1024
// Workspace (72,433,664 bytes), time-multiplexed regions (liveness checked):
//   sp    [0, 4.73M)          phase A            | T fuse-ping [0,33.55M) after corr
//   invd  [4.73M, 5.26M)                         | Bp pair [0,37.75M) after fuse2
//   Bf    [5.26M, 43.0M)      corr B pair        | sm [0,16.78M) after deconv
//   yup   [37.75M, 54.53M)    after corr         | P3 pair [16.78M,33.55M) phase C/D
//   a1    [33.55M, 50.33M)    after yup pair     | x-pair [50.33M,67.11M) after yup dead
//   wts   [67.11M, 68.98M)    whole run
//   m0/mm [72.37M, 72.43M)    whole run

#define BOFF_SP      0
#define BOFF_INVD    4734976
#define BOFF_BFH     5259264
#define BOFF_BFL     24133632
#define BOFF_T       0
#define BOFF_BPH     0
#define BOFF_BPL     18874368
#define BOFF_YUP     37748736
#define BOFF_SM      0
#define BOFF_P3H     16777216
#define BOFF_P3L     25165824
#define BOFF_A1      33554432
#define BOFF_XH      50331648
#define BOFF_XL      58720256
#define BOFF_WT1H    67108864
#define BOFF_WT1L    67403776
#define BOFF_WT2H    67698688
#define BOFF_WT2L    68288512
#define BOFF_PW1B    68878336
#define BOFF_PW2B    68911104
#define BOFF_M0      72368128
#define BOFF_MM      72400896

typedef float f32x4 __attribute__((ext_vector_type(4)));
typedef short bf16x8 __attribute__((ext_vector_type(8)));

__device__ __forceinline__ short f2bf(float f) {
    unsigned u = __float_as_uint(f);
    unsigned r = u + 0x7FFFu + ((u >> 16) & 1u);
    return (short)(r >> 16);
}
__device__ __forceinline__ float bf2f(short s) {
    return __uint_as_float(((unsigned)(unsigned short)s) << 16);
}
__device__ __forceinline__ void cvt8(const float4 v0, const float4 v1, bf16x8& h, bf16x8& l) {
    float a[8] = {v0.x, v0.y, v0.z, v0.w, v1.x, v1.y, v1.z, v1.w};
#pragma unroll
    for (int u = 0; u < 8; ++u) {
        short hh = f2bf(a[u]);
        h[u] = hh;
        l[u] = f2bf(a[u] - bf2f(hh));
    }
}

__global__ __launch_bounds__(256) void k_mask_pool(const float* __restrict__ mask, float* __restrict__ m0) {
    int blk = blockIdx.x;
    int b = blk >> 10, pq = blk & 1023, p = pq >> 5, q = pq & 31;
    int t = threadIdx.x, dy = t >> 4, dx = t & 15;
    float v = mask[((size_t)(b * 512 + p * 16 + dy)) * 512 + q * 16 + dx];
#pragma unroll
    for (int o = 32; o; o >>= 1) v = fmaxf(v, __shfl_xor(v, o));
    __shared__ float s[4];
    if ((t & 63) == 0) s[t >> 6] = v;
    __syncthreads();
    if (t == 0) m0[blk] = fmaxf(fmaxf(s[0], s[1]), fmaxf(s[2], s[3]));
}

__global__ void k_mask_dilate(const float* __restrict__ m0, float* __restrict__ mm) {
    int idx = blockIdx.x * 256 + threadIdx.x;
    if (idx >= 8192) return;
    int b = idx >> 10, pq = idx & 1023, p = pq >> 5, q = pq & 31;
    float v = -1e30f;
    for (int di = -1; di <= 1; ++di)
        for (int dj = -1; dj <= 1; ++dj) {
            int pp = p + di, qq = q + dj;
            if (pp >= 0 && pp < 32 && qq >= 0 && qq < 32)
                v = fmaxf(v, m0[(b << 10) + pp * 32 + qq]);
        }
    mm[idx] = 1.0f - v;
}

__global__ void k_srcpad(const float* __restrict__ x, float* __restrict__ sp) {
    int idx = blockIdx.x * 256 + threadIdx.x;
    if (idx >= 8 * 34 * 34 * 128) return;
    int c = idx & 127;
    int r = idx >> 7;
    int xx = r % 34; r /= 34;
    int yy = r % 34; int b = r / 34;
    float v = 0.f;
    if (yy >= 1 && yy <= 32 && xx >= 1 && xx <= 32)
        v = x[(((size_t)(b * 64 + (yy - 1) * 2)) * 64 + (xx - 1) * 2) * 128 + c];
    sp[idx] = v;
}

__global__ void k_invd(const float* __restrict__ sp, float* __restrict__ invd) {
    int idx = blockIdx.x * 256 + threadIdx.x;
    if (idx >= 1024 * 128) return;
    int c = idx & 127, l = idx >> 7, lh = l >> 5, lw = l & 31;
    float s = 0.f;
    for (int b = 0; b < 8; ++b)
#pragma unroll
        for (int i = 0; i < 3; ++i)
#pragma unroll
            for (int j = 0; j < 3; ++j) {
                float v = sp[(((size_t)(b * 34 + lh + i)) * 34 + (lw + j)) * 128 + c];
                s += v * v;
            }
    invd[idx] = 1.0f / fmaxf(s, 1e-8f);
}

// Bf[b][l][ij][c] = sp[b][lh+i][lw+j][c] * invd[l][c], split bf16 pair. 1,179,648 threads x 8 elems.
__global__ void k_corr_B(const float* __restrict__ sp, const float* __restrict__ invd,
                         short* __restrict__ bh, short* __restrict__ bl) {
    int idx = blockIdx.x * 256 + threadIdx.x;
    int c8 = idx & 15; int rest = idx >> 4;
    int ij = rest % 9; int rest2 = rest / 9;
    int l = rest2 & 1023, b = rest2 >> 10;
    int lh = l >> 5, lw = l & 31;
    int i = (ij >= 6) ? 2 : (ij >= 3 ? 1 : 0);
    int j = ij - 3 * i;
    int c0 = c8 * 8;
    const float* s = sp + (((size_t)(b * 34 + lh + i)) * 34 + (lw + j)) * 128 + c0;
    const float* dv = invd + l * 128 + c0;
    bf16x8 h, lo;
#pragma unroll
    for (int u = 0; u < 8; ++u) {
        float v = s[u] * dv[u];
        short hh = f2bf(v);
        h[u] = hh;
        lo[u] = f2bf(v - bf2f(hh));
    }
    size_t off = ((size_t)(b * 1024 + l)) * 1152 + ij * 128 + c0;
    *reinterpret_cast<bf16x8*>(bh + off) = h;
    *reinterpret_cast<bf16x8*>(bl + off) = lo;
}

// Bp[b][ij][c][l] = x[b][2lh+ip][2lw+jp][c] (0 OOB), split bf16 pair. 1,179,648 threads x 8 l's.
__global__ void k_deconv_B(const float* __restrict__ x, short* __restrict__ bh, short* __restrict__ bl) {
    int idx = blockIdx.x * 256 + threadIdx.x;
    int l8 = idx & 127; int rest = idx >> 7;
    int c = rest & 127; int rest2 = rest >> 7;
    int ij = rest2 % 9; int b = rest2 / 9;
    int ip = (ij >= 6) ? 2 : (ij >= 3 ? 1 : 0);
    int jp = ij - 3 * ip;
    int l0 = l8 * 8;
    int lh = l0 >> 5, lw0 = l0 & 31;
    int rr = 2 * lh + ip;
    bf16x8 h, lo;
#pragma unroll
    for (int u = 0; u < 8; ++u) {
        int ss = 2 * (lw0 + u) + jp;
        float v = (rr < 64 && ss < 64) ? x[(((size_t)(b * 64 + rr)) * 64 + ss) * 128 + c] : 0.f;
        short hh = f2bf(v);
        h[u] = hh;
        lo[u] = f2bf(v - bf2f(hh));
    }
    size_t off = (((size_t)(b * 9 + ij)) * 128 + c) * 1024 + l0;
    *reinterpret_cast<bf16x8*>(bh + off) = h;
    *reinterpret_cast<bf16x8*>(bl + off) = lo;
}

// corr MFMA: per batch y[pq,l] = sum_k A[pq,k]*B[k,l]; M=1024,N=1024,K=1152.
// A staged from sp f32 (converted in LDS), B from Bf pair. C-tile 64x128, 4 waves split N.
__global__ __launch_bounds__(256) void k_corr_mfma(const float* __restrict__ sp,
                                                   const short* __restrict__ bfh,
                                                   const short* __restrict__ bfl,
                                                   float* __restrict__ outy) {
    const int b = blockIdx.z, tm = blockIdx.y, tn = blockIdx.x;
    __shared__ short Ah[64][32];
    __shared__ short Al[64][32];
    const int tid = threadIdx.x;
    const int w = tid >> 6, lane = tid & 63, m = lane & 15, g = lane >> 4;
    f32x4 acc[4][2];
#pragma unroll
    for (int mf = 0; mf < 4; ++mf)
#pragma unroll
        for (int nn = 0; nn < 2; ++nn) acc[mf][nn] = f32x4{0.f, 0.f, 0.f, 0.f};
    const int srow = tid >> 2, scc = (tid & 3) * 8;
    const int pq = tm * 64 + srow, p = pq >> 5, q = pq & 31;
    const int col0 = tn * 128 + w * 32 + m;
    const size_t bB = (size_t)b * 1024;
    for (int kt = 0; kt < 1152; kt += 32) {
        int ij = kt >> 7;
        int i = (ij >= 6) ? 2 : (ij >= 3 ? 1 : 0);
        int j = ij - 3 * i;
        int c0 = (kt & 127) + scc;
        const float* s = sp + (((size_t)(b * 34 + p + i)) * 34 + (q + j)) * 128 + c0;
        float4 v0 = *reinterpret_cast<const float4*>(s);
        float4 v1 = *reinterpret_cast<const float4*>(s + 4);
        bf16x8 hh, ll;
        cvt8(v0, v1, hh, ll);
        __syncthreads();
        *reinterpret_cast<bf16x8*>(&Ah[srow][scc]) = hh;
        *reinterpret_cast<bf16x8*>(&Al[srow][scc]) = ll;
        __syncthreads();
        bf16x8 ah[4], al[4];
#pragma unroll
        for (int mf = 0; mf < 4; ++mf) {
            ah[mf] = *reinterpret_cast<const bf16x8*>(&Ah[mf * 16 + m][g * 8]);
            al[mf] = *reinterpret_cast<const bf16x8*>(&Al[mf * 16 + m][g * 8]);
        }
#pragma unroll
        for (int nn = 0; nn < 2; ++nn) {
            size_t off = (bB + col0 + nn * 16) * 1152 + kt + g * 8;
            bf16x8 bh = *reinterpret_cast<const bf16x8*>(bfh + off);
            bf16x8 bl = *reinterpret_cast<const bf16x8*>(bfl + off);
#pragma unroll
            for (int mf = 0; mf < 4; ++mf) {
                acc[mf][nn] = __builtin_amdgcn_mfma_f32_16x16x32_bf16(ah[mf], bh, acc[mf][nn], 0, 0, 0);
                acc[mf][nn] = __builtin_amdgcn_mfma_f32_16x16x32_bf16(al[mf], bh, acc[mf][nn], 0, 0, 0);
                acc[mf][nn] = __builtin_amdgcn_mfma_f32_16x16x32_bf16(ah[mf], bl, acc[mf][nn], 0, 0, 0);
            }
        }
    }
#pragma unroll
    for (int mf = 0; mf < 4; ++mf) {
        int row = tm * 64 + mf * 16 + g * 4;
#pragma unroll
        for (int nn = 0; nn < 2; ++nn) {
            int col = col0 + nn * 16;
#pragma unroll
            for (int r = 0; r < 4; ++r)
                outy[((size_t)b << 20) + (size_t)(row + r) * 1024 + col] = acc[mf][nn][r];
        }
    }
}

// deconv MFMA: per batch Z[uv,kcol] = sum_l y[uv,l]*Bp[kcol,l]; M=1024,N=1152,K=1024.
// A staged from softmax probs f32, B from Bp pair. Epilogue: atomic scatter into yup.
__global__ __launch_bounds__(256) void k_deconv_mfma(const float* __restrict__ yprob,
                                                     const short* __restrict__ bph,
                                                     const short* __restrict__ bpl,
                                                     float* __restrict__ yup) {
    const int b = blockIdx.z, tm = blockIdx.y, tn = blockIdx.x;   // tn = ij in 0..8
    __shared__ short Ah[64][32];
    __shared__ short Al[64][32];
    const int tid = threadIdx.x;
    const int w = tid >> 6, lane = tid & 63, m = lane & 15, g = lane >> 4;
    f32x4 acc[4][2];
#pragma unroll
    for (int mf = 0; mf < 4; ++mf)
#pragma unroll
        for (int nn = 0; nn < 2; ++nn) acc[mf][nn] = f32x4{0.f, 0.f, 0.f, 0.f};
    const int srow = tid >> 2, scc = (tid & 3) * 8;
    const int uvs = tm * 64 + srow;
    const int col0 = tn * 128 + w * 32 + m;
    for (int kt = 0; kt < 1024; kt += 32) {
        const float* s = yprob + ((size_t)b << 20) + (size_t)uvs * 1024 + kt + scc;
        float4 v0 = *reinterpret_cast<const float4*>(s);
        float4 v1 = *reinterpret_cast<const float4*>(s + 4);
        bf16x8 hh, ll;
        cvt8(v0, v1, hh, ll);
        __syncthreads();
        *reinterpret_cast<bf16x8*>(&Ah[srow][scc]) = hh;
        *reinterpret_cast<bf16x8*>(&Al[srow][scc]) = ll;
        __syncthreads();
        bf16x8 ah[4], al[4];
#pragma unroll
        for (int mf = 0; mf < 4; ++mf) {
            ah[mf] = *reinterpret_cast<const bf16x8*>(&Ah[mf * 16 + m][g * 8]);
            al[mf] = *reinterpret_cast<const bf16x8*>(&Al[mf * 16 + m][g * 8]);
        }
#pragma unroll
        for (int nn = 0; nn < 2; ++nn) {
            size_t off = ((size_t)b * 1152 + col0 + nn * 16) * 1024 + kt + g * 8;
            bf16x8 bh = *reinterpret_cast<const bf16x8*>(bph + off);
            bf16x8 bl = *reinterpret_cast<const bf16x8*>(bpl + off);
#pragma unroll
            for (int mf = 0; mf < 4; ++mf) {
                acc[mf][nn] = __builtin_amdgcn_mfma_f32_16x16x32_bf16(ah[mf], bh, acc[mf][nn], 0, 0, 0);
                acc[mf][nn] = __builtin_amdgcn_mfma_f32_16x16x32_bf16(al[mf], bh, acc[mf][nn], 0, 0, 0);
                acc[mf][nn] = __builtin_amdgcn_mfma_f32_16x16x32_bf16(ah[mf], bl, acc[mf][nn], 0, 0, 0);
            }
        }
    }
    const int ip = (tn >= 6) ? 2 : (tn >= 3 ? 1 : 0);
    const int jp = tn - 3 * ip;
#pragma unroll
    for (int mf = 0; mf < 4; ++mf) {
        int uvb = tm * 64 + mf * 16 + g * 4;
#pragma unroll
        for (int nn = 0; nn < 2; ++nn) {
            int c = w * 32 + nn * 16 + m;
#pragma unroll
            for (int r = 0; r < 4; ++r) {
                int uv = uvb + r;
                int uu = uv >> 5, vv = uv & 31;
                int P = 2 * uu + ip, Q = 2 * vv + jp;
                if (P < 64 && Q < 64)
                    atomicAdd(&yup[(((size_t)(b * 64 + P)) * 64 + Q) * 128 + c], acc[mf][nn][r]);
            }
        }
    }
}

__global__ void k_fuse1(const float* __restrict__ in, float* __restrict__ out) {
    size_t idx = (size_t)blockIdx.x * 256 + threadIdx.x;
    if (idx >= (size_t)8 * 1024 * 1024) return;
    int t = (int)(idx & 1023);
    int s = (int)((idx >> 10) & 1023);
    int b = (int)(idx >> 20);
    const float* base = in + ((size_t)b << 20);
    float v = base[(size_t)s * 1024 + t];
    if (s > 0 && t > 0) v += base[(size_t)(s - 1) * 1024 + (t - 1)];
    if (s < 1023 && t < 1023) v += base[(size_t)(s + 1) * 1024 + (t + 1)];
    out[idx] = v;
}

__global__ void k_fuse2(const float* __restrict__ in, float* __restrict__ out) {
    size_t idx = (size_t)blockIdx.x * 256 + threadIdx.x;
    if (idx >= (size_t)8 * 1024 * 1024) return;
    int t = (int)(idx & 1023);
    int s = (int)((idx >> 10) & 1023);
    int b = (int)(idx >> 20);
    int m0 = ((s & 31) << 5) + (s >> 5);
    int n0 = ((t & 31) << 5) + (t >> 5);
    const float* base = in + ((size_t)b << 20);
    float v = 0.f;
#pragma unroll
    for (int d = -1; d <= 1; ++d) {
        int m = m0 + d, n = n0 + d;
        if (m >= 0 && m < 1024 && n >= 0 && n < 1024)
            v += base[(size_t)(((m & 31) << 5) + (m >> 5)) * 1024 + (((n & 31) << 5) + (n >> 5))];
    }
    out[idx] = v;
}

__global__ __launch_bounds__(256) void k_softmax1024(const float* __restrict__ yv,
                                                     const float* __restrict__ mm,
                                                     float* __restrict__ outc) {
    int row = blockIdx.x;
    const float* base = yv + (size_t)row * 1024;
    float mmv = mm[row];
    int t = threadIdx.x;
    float vals[4];
    float mx = -1e30f;
#pragma unroll
    for (int i = 0; i < 4; ++i) {
        vals[i] = base[t + i * 256] * mmv * 10.0f;
        mx = fmaxf(mx, vals[i]);
    }
#pragma unroll
    for (int o = 32; o; o >>= 1) mx = fmaxf(mx, __shfl_xor(mx, o));
    __shared__ float red[8];
    if ((t & 63) == 0) red[t >> 6] = mx;
    __syncthreads();
    mx = fmaxf(fmaxf(red[0], red[1]), fmaxf(red[2], red[3]));
    float s = 0.f;
#pragma unroll
    for (int i = 0; i < 4; ++i) {
        vals[i] = expf(vals[i] - mx);
        s += vals[i];
    }
#pragma unroll
    for (int o = 32; o; o >>= 1) s += __shfl_xor(s, o);
    if ((t & 63) == 0) red[4 + (t >> 6)] = s;
    __syncthreads();
    s = red[4] + red[5] + red[6] + red[7];
    float inv = mmv / s;
#pragma unroll
    for (int i = 0; i < 4; ++i)
        outc[(size_t)row * 1024 + t + i * 256] = vals[i] * inv;
}

// float image -> bf16 hi/lo planes (4,194,304 elems, 4/thread)
__global__ __launch_bounds__(256) void k_pair(const float* __restrict__ in,
                                              short* __restrict__ hi, short* __restrict__ lo) {
    int idx = blockIdx.x * 256 + threadIdx.x;
    float4 v = reinterpret_cast<const float4*>(in)[idx];
    short4 h, L;
    float f, r;
    f = v.x; h.x = f2bf(f); r = f - bf2f(h.x); L.x = f2bf(r);
    f = v.y; h.y = f2bf(f); r = f - bf2f(h.y); L.y = f2bf(r);
    f = v.z; h.z = f2bf(f); r = f - bf2f(h.z); L.z = f2bf(r);
    f = v.w; h.w = f2bf(f); r = f - bf2f(h.w); L.w = f2bf(r);
    reinterpret_cast<short4*>(hi)[idx] = h;
    reinterpret_cast<short4*>(lo)[idx] = L;
}

__global__ void k_wt_pair(const float* __restrict__ w, short* __restrict__ hi,
                          short* __restrict__ lo, int CI) {
    int idx = blockIdx.x * 256 + threadIdx.x;
    if (idx >= 9 * CI * 128) return;
    int ci = idx % CI; int rest = idx / CI;
    int co = rest & 127; int ij = rest >> 7;
    float v = w[((size_t)ij * CI + ci) * 128 + co];
    short h = f2bf(v);
    hi[idx] = h;
    lo[idx] = f2bf(v - bf2f(h));
}

__global__ void k_pw_bf16(const float* __restrict__ pw, short* __restrict__ out, int n) {
    int idx = blockIdx.x * 256 + threadIdx.x;
    if (idx < n) out[idx] = f2bf(pw[idx]);
}

template <int CI>
__global__ __launch_bounds__(128) void k_dwpw_sm(const float* __restrict__ in0,
                                                 const float* __restrict__ in1,
                                                 const float* __restrict__ dwW,
                                                 const short* __restrict__ pwb,
                                                 const float* __restrict__ db,
                                                 float* __restrict__ smout) {
    int pix = blockIdx.x;
    int b = pix >> 12, P = (pix >> 6) & 63, Q = pix & 63;
    __shared__ float row[CI];
    __shared__ float red[4];
    int t = threadIdx.x;
    for (int c = t; c < CI; c += 128) {
        float acc = 0.f;
#pragma unroll
        for (int i = 0; i < 3; ++i) {
            int rr = P + i - 1;
            if (rr < 0 || rr > 63) continue;
#pragma unroll
            for (int j = 0; j < 3; ++j) {
                int ss = Q + j - 1;
                if (ss < 0 || ss > 63) continue;
                float v = (CI == 128 || c < 128)
                              ? in0[(((size_t)(b * 64 + rr)) * 64 + ss) * 128 + (c & 127)]
                              : in1[(((size_t)(b * 64 + rr)) * 64 + ss) * 128 + (c - 128)];
                acc = fmaf(v, dwW[(i * 3 + j) * CI + c], acc);
            }
        }
        row[c] = acc;
    }
    __syncthreads();
    float acc = db[t];
#pragma unroll 8
    for (int ci = 0; ci < CI; ++ci)
        acc = fmaf(row[ci], bf2f(pwb[(size_t)ci * 128 + t]), acc);
    float m = acc;
#pragma unroll
    for (int o = 32; o; o >>= 1) m = fmaxf(m, __shfl_xor(m, o));
    if ((t & 63) == 0) red[t >> 6] = m;
    __syncthreads();
    m = fmaxf(red[0], red[1]);
    float e = expf(acc - m);
    float s = e;
#pragma unroll
    for (int o = 32; o; o >>= 1) s += __shfl_xor(s, o);
    if ((t & 63) == 0) red[2 + (t >> 6)] = s;
    __syncthreads();
    s = red[2] + red[3];
    smout[(size_t)pix * 128 + t] = e / s;
}

// MFMA split-bf16 implicit-GEMM 3x3 conv + bias + elu + gate multiply
template <int CI>
__global__ __launch_bounds__(256) void k_conv_mfma(const short* __restrict__ in0h,
                                                   const short* __restrict__ in0l,
                                                   const short* __restrict__ in1h,
                                                   const short* __restrict__ in1l,
                                                   const short* __restrict__ wh,
                                                   const short* __restrict__ wl,
                                                   const float* __restrict__ bias,
                                                   const float* __restrict__ sm,
                                                   float* __restrict__ out) {
    const int P = blockIdx.x, b = blockIdx.y;
    const int wv = threadIdx.x >> 6, l = threadIdx.x & 63;
    const int m = l & 15, g = l >> 4;
    bf16x8 zf;
#pragma unroll
    for (int t = 0; t < 8; ++t) zf[t] = 0;
    f32x4 acc[4][2];
#pragma unroll
    for (int mt = 0; mt < 4; ++mt)
#pragma unroll
        for (int nn = 0; nn < 2; ++nn) acc[mt][nn] = f32x4{0.f, 0.f, 0.f, 0.f};

    const size_t imgbase = ((size_t)b * 64) * 64 * 128;
#pragma unroll
    for (int i = 0; i < 3; ++i) {
        const int row = P + i - 1;
        if (row < 0 || row > 63) continue;
#pragma unroll
        for (int j = 0; j < 3; ++j) {
            const int ij = i * 3 + j;
            int Qp[4];
            bool okp[4];
#pragma unroll
            for (int mt = 0; mt < 4; ++mt) {
                int Q = mt * 16 + m + j - 1;
                okp[mt] = (Q >= 0) && (Q < 64);
                Qp[mt] = okp[mt] ? Q : 0;
            }
#pragma unroll
            for (int ci0 = 0; ci0 < CI; ci0 += 32) {
                const short* sh = (CI == 256 && ci0 >= 128) ? in1h : in0h;
                const short* sl = (CI == 256 && ci0 >= 128) ? in1l : in0l;
                const int cil = (CI == 256 && ci0 >= 128) ? (ci0 - 128) : ci0;
                bf16x8 ah[4], al[4];
#pragma unroll
                for (int mt = 0; mt < 4; ++mt) {
                    size_t off = imgbase + ((size_t)row * 64 + Qp[mt]) * 128 + cil + g * 8;
                    ah[mt] = okp[mt] ? *reinterpret_cast<const bf16x8*>(sh + off) : zf;
                    al[mt] = okp[mt] ? *reinterpret_cast<const bf16x8*>(sl + off) : zf;
                }
#pragma unroll
                for (int nn = 0; nn < 2; ++nn) {
                    const int co = (wv * 2 + nn) * 16 + m;
                    const size_t woff = ((size_t)ij * 128 + co) * CI + ci0 + g * 8;
                    bf16x8 bh = *reinterpret_cast<const bf16x8*>(wh + woff);
                    bf16x8 bl = *reinterpret_cast<const bf16x8*>(wl + woff);
#pragma unroll
                    for (int mt = 0; mt < 4; ++mt) {
                        acc[mt][nn] = __builtin_amdgcn_mfma_f32_16x16x32_bf16(ah[mt], bh, acc[mt][nn], 0, 0, 0);
                        acc[mt][nn] = __builtin_amdgcn_mfma_f32_16x16x32_bf16(ah[mt], bl, acc[mt][nn], 0, 0, 0);
                        acc[mt][nn] = __builtin_amdgcn_mfma_f32_16x16x32_bf16(al[mt], bh, acc[mt][nn], 0, 0, 0);
                    }
                }
            }
        }
    }
#pragma unroll
    for (int nn = 0; nn < 2; ++nn) {
        const int co = (wv * 2 + nn) * 16 + m;
        const float bb = bias[co];
#pragma unroll
        for (int mt = 0; mt < 4; ++mt) {
#pragma unroll
            for (int r = 0; r < 4; ++r) {
                int Q = mt * 16 + g * 4 + r;
                size_t pix = ((size_t)b * 64 + P) * 64 + Q;
                float z = acc[mt][nn][r] + bb;
                z = z > 0.f ? z : expm1f(z);
                out[pix * 128 + co] = z * sm[pix * 128 + co];
            }
        }
    }
}

extern "C" void kernel_launch(void* const* d_in, const int* in_sizes, int n_in,
                              void* d_out, int out_size, void* d_ws, size_t ws_size,
                              hipStream_t stream) {
    const float* x    = (const float*)d_in[0];
    const float* mask = (const float*)d_in[1];
    const float* w1   = (const float*)d_in[2];
    const float* b1   = (const float*)d_in[3];
    const float* dw1  = (const float*)d_in[4];
    const float* pw1  = (const float*)d_in[5];
    const float* db1  = (const float*)d_in[6];
    const float* w2   = (const float*)d_in[7];
    const float* b2   = (const float*)d_in[8];
    const float* dw2  = (const float*)d_in[9];
    const float* pw2  = (const float*)d_in[10];
    const float* db2  = (const float*)d_in[11];

    float* out_a = (float*)d_out;            // (8,64,64,128)
    float* out_c = out_a + 4194304;          // (8,32,32,1024)

    char* wsb = (char*)d_ws;
    float* sp   = (float*)(wsb + BOFF_SP);
    float* invd = (float*)(wsb + BOFF_INVD);
    short* bfh  = (short*)(wsb + BOFF_BFH);
    short* bfl  = (short*)(wsb + BOFF_BFL);
    float* Tbuf = (float*)(wsb + BOFF_T);
    short* bph  = (short*)(wsb + BOFF_BPH);
    short* bpl  = (short*)(wsb + BOFF_BPL);
    float* yup  = (float*)(wsb + BOFF_YUP);
    float* smb  = (float*)(wsb + BOFF_SM);
    short* p3h  = (short*)(wsb + BOFF_P3H);
    short* p3l  = (short*)(wsb + BOFF_P3L);
    float* a1   = (float*)(wsb + BOFF_A1);
    short* xh   = (short*)(wsb + BOFF_XH);
    short* xl   = (short*)(wsb + BOFF_XL);
    short* wt1h = (short*)(wsb + BOFF_WT1H);
    short* wt1l = (short*)(wsb + BOFF_WT1L);
    short* wt2h = (short*)(wsb + BOFF_WT2H);
    short* wt2l = (short*)(wsb + BOFF_WT2L);
    short* pw1b = (short*)(wsb + BOFF_PW1B);
    short* pw2b = (short*)(wsb + BOFF_PW2B);
    float* m0   = (float*)(wsb + BOFF_M0);
    float* mmb  = (float*)(wsb + BOFF_MM);

    // phase A: mask + correlation (MFMA) + fuse + softmax
    k_mask_pool<<<8192, 256, 0, stream>>>(mask, m0);
    k_mask_dilate<<<32, 256, 0, stream>>>(m0, mmb);
    k_srcpad<<<4624, 256, 0, stream>>>(x, sp);
    k_invd<<<512, 256, 0, stream>>>(sp, invd);
    k_wt_pair<<<576, 256, 0, stream>>>(w1, wt1h, wt1l, 128);
    k_wt_pair<<<1152, 256, 0, stream>>>(w2, wt2h, wt2l, 256);
    k_pw_bf16<<<64, 256, 0, stream>>>(pw1, pw1b, 16384);
    k_pw_bf16<<<128, 256, 0, stream>>>(pw2, pw2b, 32768);
    k_corr_B<<<4608, 256, 0, stream>>>(sp, invd, bfh, bfl);
    k_corr_mfma<<<dim3(8, 16, 8), 256, 0, stream>>>(sp, bfh, bfl, out_c);
    k_fuse1<<<32768, 256, 0, stream>>>(out_c, Tbuf);
    k_fuse2<<<32768, 256, 0, stream>>>(Tbuf, out_c);
    k_deconv_B<<<4608, 256, 0, stream>>>(x, bph, bpl);
    k_softmax1024<<<8192, 256, 0, stream>>>(out_c, mmb, out_c);   // in-place, row-local
    // phase B: deconv (MFMA) -> yup
    hipMemsetAsync(yup, 0, (size_t)4194304 * sizeof(float), stream);
    k_deconv_mfma<<<dim3(9, 16, 8), 256, 0, stream>>>(out_c, bph, bpl, yup);
    // phase C: gated conv 1
    k_dwpw_sm<128><<<32768, 128, 0, stream>>>(yup, nullptr, dw1, pw1b, db1, smb);
    k_pair<<<4096, 256, 0, stream>>>(yup, p3h, p3l);
    k_pair<<<4096, 256, 0, stream>>>(x, xh, xl);                  // after yup dead (region overlap)
    k_conv_mfma<128><<<dim3(64, 8), 256, 0, stream>>>(p3h, p3l, nullptr, nullptr,
                                                      wt1h, wt1l, b1, smb, a1);
    // phase D: gated conv 2 (concat(a1, x))
    k_dwpw_sm<256><<<32768, 128, 0, stream>>>(a1, x, dw2, pw2b, db2, smb);
    k_pair<<<4096, 256, 0, stream>>>(a1, p3h, p3l);
    k_conv_mfma<256><<<dim3(64, 8), 256, 0, stream>>>(p3h, p3l, xh, xl,
                                                      wt2h, wt2l, b2, smb, out_a);
}